// Round 14
// baseline (116.612 us; speedup 1.0000x reference)
//
#include <hip/hip_runtime.h>

// AffinitySideLoss: B=4, E=12, H=W=512, S=8 offsets, output = 1 float scalar.
// d_in[0] = input_ float32 [4,12,512,512]
// d_in[1] = target int32   [4,1,512,512]
// d_in[2] = offsets int32  [8,2]  (values in [-27,0))
// d_out   = float32 [1]
// d_ws    = float partial[16][512] (32 KB) + unsigned counter @ +32768
//
// R14 = R9 main (best bench total, 41.9 us) + fused last-block reduction.
// R9 structure: 16x128 supertile, single-LDS-buffer halo (44x156/channel),
// reg-staged staging (plain f4 loads -> ds_write_b128; global_load_lds
// bypasses the Infinity Cache - R6/R8 evidence), 13 channels (12 emb + seg
// bits), all 9 reads/px/channel from LDS. ~183 MB L2 demand vs 490 MB for
// direct-load kernels (the ~45us wall). Fusion: each block stores 16
// partials, device-scope release fence + atomicAdd on a counter; the 512th
// block reduces all partials in double (agent-scope atomic loads to cross
// non-coherent per-XCD L2s) and writes the scalar. Deterministic: reduced
// set and order are fixed regardless of which block finishes last.

typedef float f2 __attribute__((ext_vector_type(2)));
typedef float f4 __attribute__((ext_vector_type(4)));

#define HWSZ   262144     // 512*512
#define NE     12
#define NC     13         // 12 emb channels + 1 seg channel
#define NS     8
#define TROWS  16
#define TCOLS  128
#define NBLK   512        // 4 batches x 32 row-tiles x 4 col-tiles
#define HROWS  44         // rows r0-28 .. r0+15
#define HCOLS  156        // cols c0-28 .. c0+127
#define HSZ    (HROWS * HCOLS)   // 6864 floats
#define NCHUNK (HCOLS / 4)       // 39 f4-chunks per halo row
#define NSLOT  (HSZ / 4)         // 1716 f4 slots

__global__ __launch_bounds__(512) void affloss_main(
    const float* __restrict__ emb, const int* __restrict__ seg,
    const int* __restrict__ offs, float* __restrict__ partial,
    unsigned* __restrict__ counter, float* __restrict__ out) {
  __shared__ f4 buf4[NSLOT];            // 27,456 B halo buffer
  __shared__ float red[8][16];
  __shared__ double csumS[16];
  __shared__ unsigned lastflag;
  float* buf = (float*)buf4;

  // XCD swizzle (bijective, 512 % 8 == 0): contiguous tile band per XCD so
  // neighbor-tile halo overlap hits that XCD's L2.
  const int bid = blockIdx.x;
  const int nb  = (bid & 7) * (NBLK / 8) + (bid >> 3);
  const int b   = nb >> 7;              // batch 0..3
  const int rem = nb & 127;             // 32 row-tiles x 4 col-tiles
  const int r0  = (rem >> 2) * TROWS;   // 0..496
  const int c0  = (rem & 3) * TCOLS;    // 0..384

  const int tid = threadIdx.x;
  const int tx  = tid & 63;             // f2 col: tile cols 2tx, 2tx+1
  const int wv  = tid >> 6;             // wave 0..7 -> tile rows wv, wv+8

  const float* embB = emb + (size_t)b * NE * HWSZ;
  const int*   segB = seg + (size_t)b * HWSZ;

  int oyv[NS], oxv[NS];
  #pragma unroll
  for (int s = 0; s < NS; ++s) { oyv[s] = offs[2 * s]; oxv[s] = offs[2 * s + 1]; }

  // Per-thread staging geometry: slots tid, tid+512, tid+1024, tid+1536.
  // slot -> halo (row, 4-col chunk); global row clamps at 0 (replication);
  // negative col chunk (c0==0, cols<28) is entirely col<0 -> splat col 0.
  int srow[4], sgc[4];
  #pragma unroll
  for (int k = 0; k < 4; ++k) {
    const int slot = tid + k * 512;
    const int rr = slot / NCHUNK;
    const int ch = slot - rr * NCHUNK;
    int gr = r0 - 28 + rr; gr = gr < 0 ? 0 : gr;
    srow[k] = gr;
    sgc[k] = c0 - 28 + 4 * ch;
  }
  const bool s3 = tid < (NSLOT - 3 * 512);   // 180 threads own a 4th slot

  auto stage_load = [&](int e, f4* r) {
    const float* p = (e < NE) ? (embB + (size_t)e * HWSZ) : (const float*)segB;
    #pragma unroll
    for (int k = 0; k < 4; ++k) {
      if (k == 3 && !s3) continue;
      const float* rowp = p + srow[k] * 512;
      if (sgc[k] >= 0) {
        r[k] = *reinterpret_cast<const f4*>(rowp + sgc[k]);   // 16B aligned
      } else {
        const float v = rowp[0];                              // replication splat
        r[k] = f4{v, v, v, v};
      }
    }
  };
  auto stage_write = [&](const f4* r) {
    #pragma unroll
    for (int k = 0; k < 4; ++k) {
      if (k == 3 && !s3) continue;
      buf4[tid + k * 512] = r[k];                             // ds_write_b128
    }
  };

  f2 ssv[2][NS];
  #pragma unroll
  for (int q = 0; q < 2; ++q)
    #pragma unroll
    for (int s = 0; s < NS; ++s) ssv[q][s] = f2{0.f, 0.f};
  float numa[NS], dena[NS];
  #pragma unroll
  for (int s = 0; s < NS; ++s) { numa[s] = 0.f; dena[s] = 0.f; }

  f4 r[4];
  stage_load(0, r);

  for (int e = 0; e < NC; ++e) {
    __syncthreads();                   // readers of buf (channel e-1) done
    stage_write(r);                    // waits only on r's loads (vmcnt)
    __syncthreads();                   // writes visible
    if (e + 1 < NC) stage_load(e + 1, r);   // flies during compute below

    if (e < NE) {
      #pragma unroll
      for (int q = 0; q < 2; ++q) {
        const int hr = wv + 8 * q + 28;           // halo row 28..43
        const int cb = hr * HCOLS + 28 + 2 * tx;  // center px0 idx (8B aligned)
        const f2 cc = *reinterpret_cast<const f2*>(&buf[cb]);
        #pragma unroll
        for (int s = 0; s < NS; ++s) {
          const int a = cb + oyv[s] * HCOLS + oxv[s];   // in-halo by constr.
          f2 sh; sh[0] = buf[a]; sh[1] = buf[a + 1];
          const f2 d = cc - sh;
          ssv[q][s][0] = fmaf(d[0], d[0], ssv[q][s][0]);
          ssv[q][s][1] = fmaf(d[1], d[1], ssv[q][s][1]);
        }
      }
    } else {
      // seg channel: bit-exact int compare + dice accumulation
      #pragma unroll
      for (int q = 0; q < 2; ++q) {
        const int hr = wv + 8 * q + 28;
        const int cb = hr * HCOLS + 28 + 2 * tx;
        const int tc0 = __float_as_int(buf[cb]);
        const int tc1 = __float_as_int(buf[cb + 1]);
        #pragma unroll
        for (int s = 0; s < NS; ++s) {
          const int a = cb + oyv[s] * HCOLS + oxv[s];
          const int t0 = __float_as_int(buf[a]);
          const int t1 = __float_as_int(buf[a + 1]);
          {
            const float n  = __builtin_amdgcn_sqrtf(ssv[q][s][0]);
            const float rc = fmaxf(fmaf(n, -(1.0f / 3.0f), 1.0f), 0.0f);
            const float A  = fmaf(-rc, rc, 1.0f);
            const float ta = (tc0 == t0) ? 0.f : 1.f;
            numa[s] = fmaf(A, ta, numa[s]);
            dena[s] += fmaf(A, A, ta);
          }
          {
            const float n  = __builtin_amdgcn_sqrtf(ssv[q][s][1]);
            const float rc = fmaxf(fmaf(n, -(1.0f / 3.0f), 1.0f), 0.0f);
            const float A  = fmaf(-rc, rc, 1.0f);
            const float ta = (tc1 == t1) ? 0.f : 1.f;
            numa[s] = fmaf(A, ta, numa[s]);
            dena[s] += fmaf(A, A, ta);
          }
        }
      }
    }
  }

  // block reduction: [0..7]=num, [8..15]=den
  float arr[16];
  #pragma unroll
  for (int s = 0; s < NS; ++s) { arr[s] = numa[s]; arr[8 + s] = dena[s]; }
  #pragma unroll
  for (int k = 0; k < 16; ++k) {
    float v = arr[k];
    #pragma unroll
    for (int o = 32; o > 0; o >>= 1) v += __shfl_down(v, o, 64);
    arr[k] = v;
  }
  const int lane = tid & 63;
  if (lane == 0) {
    #pragma unroll
    for (int k = 0; k < 16; ++k) red[wv][k] = arr[k];
  }
  __syncthreads();
  if (tid < 16) {
    float v = 0.f;
    #pragma unroll
    for (int w = 0; w < 8; ++w) v += red[w][tid];
    partial[tid * NBLK + blockIdx.x] = v;   // [channel][block]
  }

  // ---- fused final reduction: last block to arrive does the dice sum ----
  __threadfence();                          // release partial stores (device scope)
  if (tid == 0) {
    const unsigned old = atomicAdd(counter, 1u);   // device-scope by default
    lastflag = (old == NBLK - 1) ? 1u : 0u;
  }
  __syncthreads();
  if (lastflag) {
    __threadfence();                        // acquire side
    // wave w reduces channels 2w and 2w+1 over all 512 blocks, in double.
    #pragma unroll
    for (int cc = 0; cc < 2; ++cc) {
      const int c = 2 * wv + cc;
      double s = 0.0;
      for (int i = lane; i < NBLK; i += 64)
        s += (double)__hip_atomic_load(&partial[c * NBLK + i],
                                       __ATOMIC_RELAXED, __HIP_MEMORY_SCOPE_AGENT);
      #pragma unroll
      for (int o = 32; o > 0; o >>= 1) s += __shfl_down(s, o, 64);
      if (lane == 0) csumS[c] = s;
    }
    __syncthreads();
    if (tid == 0) {
      double total = 0.0;
      #pragma unroll
      for (int c = 0; c < 8; ++c) {
        double nu = csumS[c];
        double de = csumS[8 + c];
        if (de < 1e-7) de = 1e-7;           // maximum(den, EPS)
        total += 1.0 - 2.0 * nu / de;
      }
      out[0] = (float)total;
    }
  }
}

extern "C" void kernel_launch(void* const* d_in, const int* in_sizes, int n_in,
                              void* d_out, int out_size, void* d_ws, size_t ws_size,
                              hipStream_t stream) {
  const float* emb  = (const float*)d_in[0];
  const int*   seg  = (const int*)d_in[1];
  const int*   offs = (const int*)d_in[2];
  float*    partial = (float*)d_ws;                       // 16*512 floats = 32 KB
  unsigned* counter = (unsigned*)((char*)d_ws + 32768);   // 4 B

  hipMemsetAsync(counter, 0, sizeof(unsigned), stream);   // graph-capture safe
  affloss_main<<<NBLK, 512, 0, stream>>>(emb, seg, offs, partial,
                                         counter, (float*)d_out);
}

// Round 15
// 43.660 us; speedup vs baseline: 2.6709x; 2.6709x over previous
//
#include <hip/hip_runtime.h>

// AffinitySideLoss: B=4, E=12, H=W=512, S=8 offsets, output = 1 float scalar.
// d_in[0] = input_ float32 [4,12,512,512]
// d_in[1] = target int32   [4,1,512,512]
// d_in[2] = offsets int32  [8,2]  (values in [-27,0))
// d_out   = float32 [1]
// d_ws    = per-block partials: float [16][1024]  (64 KB)
//
// R15 = R9 (best: 41.9 us) with the ONLY change being tile 16x128 -> 16x64,
// NBLK 512 -> 1024: 4 blocks/CU instead of 2, so the per-block barrier
// stalls overlap with 3 other resident blocks. Code structure, lambdas,
// loop, and barrier discipline identical to R9 (VGPR 60 there; less state
// here). Two-kernel launch kept (R14's fused fence/atomic tail invalidated
// L2 across the XCD -> 116 us).

typedef float f2 __attribute__((ext_vector_type(2)));
typedef float f4 __attribute__((ext_vector_type(4)));

#define HWSZ   262144     // 512*512
#define NE     12
#define NC     13         // 12 emb channels + 1 seg channel
#define NS     8
#define TROWS  16
#define TCOLS  64
#define NBLK   1024       // 4 batches x 32 row-tiles x 8 col-tiles
#define HROWS  44         // rows r0-28 .. r0+15
#define HCOLS  92         // cols c0-28 .. c0+63
#define HSZ    (HROWS * HCOLS)   // 4048 floats
#define NCHUNK (HCOLS / 4)       // 23 f4-chunks per halo row
#define NSLOT  (HSZ / 4)         // 1012 f4 slots

__global__ __launch_bounds__(512) void affloss_main(
    const float* __restrict__ emb, const int* __restrict__ seg,
    const int* __restrict__ offs, float* __restrict__ partial) {
  __shared__ f4 buf4[NSLOT];            // 16,192 B halo buffer
  __shared__ float red[8][16];
  float* buf = (float*)buf4;

  // XCD swizzle (bijective, 1024 % 8 == 0): contiguous tile band per XCD so
  // neighbor-tile halo overlap hits that XCD's L2.
  const int bid = blockIdx.x;
  const int nb  = (bid & 7) * (NBLK / 8) + (bid >> 3);
  const int b   = nb >> 8;              // batch 0..3
  const int rem = nb & 255;             // 32 row-tiles x 8 col-tiles
  const int r0  = (rem >> 3) * TROWS;   // 0..496
  const int c0  = (rem & 7) * TCOLS;    // 0..448

  const int tid = threadIdx.x;
  const int tx  = tid & 31;             // f2 col: tile cols 2tx, 2tx+1
  const int row = tid >> 5;             // tile row 0..15
  const int wv  = tid >> 6;             // wave 0..7

  const float* embB = emb + (size_t)b * NE * HWSZ;
  const int*   segB = seg + (size_t)b * HWSZ;

  int oyv[NS], oxv[NS];
  #pragma unroll
  for (int s = 0; s < NS; ++s) { oyv[s] = offs[2 * s]; oxv[s] = offs[2 * s + 1]; }

  // Per-thread staging geometry: slots tid, tid+512 (2nd only for tid<500).
  // slot -> halo (row, 4-col chunk); global row clamps at 0 (replication);
  // negative col chunk (c0==0, cols<28) is entirely col<0 -> splat col 0.
  int srow[2], sgc[2];
  #pragma unroll
  for (int k = 0; k < 2; ++k) {
    const int slot = tid + k * 512;
    const int rr = slot / NCHUNK;
    const int ch = slot - rr * NCHUNK;
    int gr = r0 - 28 + rr; gr = gr < 0 ? 0 : gr;
    srow[k] = gr;
    sgc[k] = c0 - 28 + 4 * ch;
  }
  const bool s1 = tid < (NSLOT - 512);   // threads 0..499 own a 2nd slot

  auto stage_load = [&](int e, f4* r) {
    const float* p = (e < NE) ? (embB + (size_t)e * HWSZ) : (const float*)segB;
    #pragma unroll
    for (int k = 0; k < 2; ++k) {
      if (k == 1 && !s1) continue;
      const float* rowp = p + srow[k] * 512;
      if (sgc[k] >= 0) {
        r[k] = *reinterpret_cast<const f4*>(rowp + sgc[k]);   // 16B aligned
      } else {
        const float v = rowp[0];                              // replication splat
        r[k] = f4{v, v, v, v};
      }
    }
  };
  auto stage_write = [&](const f4* r) {
    buf4[tid] = r[0];                                         // ds_write_b128
    if (s1) buf4[tid + 512] = r[1];
  };

  f2 ssv[NS];
  #pragma unroll
  for (int s = 0; s < NS; ++s) ssv[s] = f2{0.f, 0.f};
  float numa[NS], dena[NS];
  #pragma unroll
  for (int s = 0; s < NS; ++s) { numa[s] = 0.f; dena[s] = 0.f; }

  const int cb = (row + 28) * HCOLS + 28 + 2 * tx;   // center px0 idx (8B aligned)

  f4 r[2];
  stage_load(0, r);

  for (int e = 0; e < NC; ++e) {
    __syncthreads();                   // readers of buf (channel e-1) done
    stage_write(r);                    // waits only on r's loads (vmcnt)
    __syncthreads();                   // writes visible
    if (e + 1 < NC) stage_load(e + 1, r);   // flies during compute below

    if (e < NE) {
      const f2 cc = *reinterpret_cast<const f2*>(&buf[cb]);
      #pragma unroll
      for (int s = 0; s < NS; ++s) {
        const int a = cb + oyv[s] * HCOLS + oxv[s];   // in-halo by constr.
        f2 sh; sh[0] = buf[a]; sh[1] = buf[a + 1];
        const f2 d = cc - sh;
        ssv[s][0] = fmaf(d[0], d[0], ssv[s][0]);
        ssv[s][1] = fmaf(d[1], d[1], ssv[s][1]);
      }
    } else {
      // seg channel: bit-exact int compare + dice accumulation
      const int tc0 = __float_as_int(buf[cb]);
      const int tc1 = __float_as_int(buf[cb + 1]);
      #pragma unroll
      for (int s = 0; s < NS; ++s) {
        const int a = cb + oyv[s] * HCOLS + oxv[s];
        const int t0 = __float_as_int(buf[a]);
        const int t1 = __float_as_int(buf[a + 1]);
        {
          const float n  = __builtin_amdgcn_sqrtf(ssv[s][0]);
          const float rc = fmaxf(fmaf(n, -(1.0f / 3.0f), 1.0f), 0.0f);
          const float A  = fmaf(-rc, rc, 1.0f);
          const float ta = (tc0 == t0) ? 0.f : 1.f;
          numa[s] = fmaf(A, ta, numa[s]);
          dena[s] += fmaf(A, A, ta);
        }
        {
          const float n  = __builtin_amdgcn_sqrtf(ssv[s][1]);
          const float rc = fmaxf(fmaf(n, -(1.0f / 3.0f), 1.0f), 0.0f);
          const float A  = fmaf(-rc, rc, 1.0f);
          const float ta = (tc1 == t1) ? 0.f : 1.f;
          numa[s] = fmaf(A, ta, numa[s]);
          dena[s] += fmaf(A, A, ta);
        }
      }
    }
  }

  // block reduction: [0..7]=num, [8..15]=den
  float arr[16];
  #pragma unroll
  for (int s = 0; s < NS; ++s) { arr[s] = numa[s]; arr[8 + s] = dena[s]; }
  #pragma unroll
  for (int k = 0; k < 16; ++k) {
    float v = arr[k];
    #pragma unroll
    for (int o = 32; o > 0; o >>= 1) v += __shfl_down(v, o, 64);
    arr[k] = v;
  }
  const int lane = tid & 63;
  if (lane == 0) {
    #pragma unroll
    for (int k = 0; k < 16; ++k) red[wv][k] = arr[k];
  }
  __syncthreads();
  if (tid < 16) {
    float v = 0.f;
    #pragma unroll
    for (int w = 0; w < 8; ++w) v += red[w][tid];
    partial[tid * NBLK + blockIdx.x] = v;   // [channel][block]
  }
}

__global__ __launch_bounds__(1024) void affloss_final(
    const float* __restrict__ partial, float* __restrict__ out) {
  __shared__ double csum[16];
  const int lane = threadIdx.x & 63, wv = threadIdx.x >> 6;  // wv = channel

  double s = 0.0;
  for (int i = lane; i < NBLK; i += 64)
    s += (double)partial[wv * NBLK + i];
  #pragma unroll
  for (int o = 32; o > 0; o >>= 1) s += __shfl_down(s, o, 64);
  if (lane == 0) csum[wv] = s;
  __syncthreads();

  if (threadIdx.x == 0) {
    double total = 0.0;
    #pragma unroll
    for (int c = 0; c < 8; ++c) {
      double num = csum[c];
      double den = csum[8 + c];
      if (den < 1e-7) den = 1e-7;            // maximum(den, EPS)
      total += 1.0 - 2.0 * num / den;
    }
    out[0] = (float)total;
  }
}

extern "C" void kernel_launch(void* const* d_in, const int* in_sizes, int n_in,
                              void* d_out, int out_size, void* d_ws, size_t ws_size,
                              hipStream_t stream) {
  const float* emb  = (const float*)d_in[0];
  const int*   seg  = (const int*)d_in[1];
  const int*   offs = (const int*)d_in[2];
  float* partial = (float*)d_ws;   // 16*1024 floats = 65,536 B

  affloss_main<<<NBLK, 512, 0, stream>>>(emb, seg, offs, partial);
  affloss_final<<<1, 1024, 0, stream>>>(partial, (float*)d_out);
}